// Round 6
// baseline (155.047 us; speedup 1.0000x reference)
//
#include <hip/hip_runtime.h>
#include <math.h>

#define B 16
#define K 256
#define Z 128
#define H 128

typedef _Float16 h2 __attribute__((ext_vector_type(2)));
union U32H2 { unsigned int u; h2 h; };

// ---------------- Kernel A: m1z = z@W1^T+b1, m2z = z@W2^T+b2 ----------------
// block 256 thr = (o:128) x (rh:2 row-groups of 4); 8 rows/block; grid 512.
// Weights staged through LDS in 32-d chunks with coalesced float2 loads.
__global__ __launch_bounds__(256) void k_lin(
    const float* __restrict__ z,
    const float* __restrict__ W1, const float* __restrict__ b1,
    const float* __restrict__ W2, const float* __restrict__ b2,
    float* __restrict__ m1z, float* __restrict__ m2z)
{
    const int tid  = threadIdx.x;
    const int o    = tid & 127;
    const int rh   = tid >> 7;
    const int row0 = blockIdx.x * 8;

    __shared__ float zs[8][Z];        // 4 KB
    __shared__ float sw1[Z][34];      // 17.4 KB: chunk [o][32d] + pad2 (bank spread)
    __shared__ float sw2[Z][34];

    {   // coalesced z stage: 8 rows x 128
        const int rr = tid >> 5, cc = (tid & 31) * 4;
        *(float4*)&zs[rr][cc] = *(const float4*)&z[(row0 + rr) * Z + cc];
    }

    float a1[4], a2[4];
    const float bb1 = b1[o], bb2 = b2[o];
#pragma unroll
    for (int r = 0; r < 4; ++r) { a1[r] = bb1; a2[r] = bb2; }

    for (int kc = 0; kc < 4; ++kc) {
        __syncthreads();              // prev chunk consumed (and zs ready, kc=0)
        // stage W1/W2 chunk: 128 rows x 16 float2 each, lane-consecutive
#pragma unroll
        for (int q = 0; q < 8; ++q) {
            const int f  = q * 256 + tid;   // float2 idx in [0,2048)
            const int oo = f >> 4;
            const int jj = (f & 15) * 2;
            *(float2*)&sw1[oo][jj] = *(const float2*)&W1[oo * Z + kc * 32 + jj];
            *(float2*)&sw2[oo][jj] = *(const float2*)&W2[oo * Z + kc * 32 + jj];
        }
        __syncthreads();
#pragma unroll
        for (int j2 = 0; j2 < 16; ++j2) {
            const float2 w1 = *(const float2*)&sw1[o][j2 * 2];
            const float2 w2 = *(const float2*)&sw2[o][j2 * 2];
#pragma unroll
            for (int r = 0; r < 4; ++r) {
                const float2 zv = *(const float2*)&zs[rh * 4 + r][kc * 32 + j2 * 2];
                a1[r] += zv.x * w1.x + zv.y * w1.y;
                a2[r] += zv.x * w2.x + zv.y * w2.y;
            }
        }
    }
#pragma unroll
    for (int r = 0; r < 4; ++r) {
        const int row = row0 + rh * 4 + r;
        m1z[row * Z + o] = a1[r];
        m2z[row * Z + o] = a2[r];
    }
}

// ---------------- Kernel B (fused): tropical max + concat GEMM ---------------
// grid (b:16, itile:32); block 256 = 4 waves; block covers 8 i x 128 d x 256 j,
// then out[i, :] = relu(concat(z,m) @ Wu^T + bu) for its 8 rows.
// Tropical inner loop in packed f16 (v_pk_add_f16 / v_pk_max_f16): lane = d-pair.
__global__ __launch_bounds__(256) void k_maxout(
    const float* __restrict__ z, const int* __restrict__ P,
    const float* __restrict__ m1z, const float* __restrict__ m2z,
    const float* __restrict__ Wu, const float* __restrict__ bu,
    float* __restrict__ out)
{
    const int b    = blockIdx.x;
    const int i0   = blockIdx.y * 8;
    const int tid  = threadIdx.x;
    const int lane = tid & 63;        // d-pair: d = 2*lane, 2*lane+1
    const int wv   = tid >> 6;        // wave -> rows 2wv, 2wv+1

    __shared__ __align__(16) char pool[128 * 128 * 2];  // 32 KB: sv then swu
    __shared__ unsigned int smask[8][K];                // 8 KB: 0 or (-inf,-inf) f16 pair
    __shared__ float xs[8][264];                        // 8.4 KB: concat(z,m) rows (+pad)
    h2    (*sv)[64]  = (h2    (*)[64])pool;             // m2z j-tile, f16 pairs
    float (*swu)[34] = (float (*)[34])pool;             // Wu chunk

    {   // xs z-part (coalesced); read early to overlap
        const int rr = tid >> 5, cc = (tid & 31) * 4;
        *(float4*)&xs[rr][cc] = *(const float4*)&z[(b * K + i0 + rr) * Z + cc];
    }
    {   // mask stage: smask[ii][j] for 8 i x 256 j
        const int ii = tid & 7;
        const int jb = tid >> 3;      // 0..31
#pragma unroll
        for (int g = 0; g < 8; ++g) {
            const int j = jb + 32 * g;
            const int pv = P[(b * K + j) * K + i0 + ii];
            smask[ii][j] = pv ? 0u : 0xFC00FC00u;   // (-inf,-inf) in f16
        }
    }

    U32H2 ninf; ninf.u = 0xFC00FC00u;
    h2 acc0 = ninf.h, acc1 = ninf.h;

    for (int jt = 0; jt < 2; ++jt) {
        __syncthreads();              // prev tile consumed (jt=0: covers z/mask stage)
        // stage sv: m2z rows [jt*128, +128) as f16 pairs; coalesced float4 reads
#pragma unroll
        for (int q = 0; q < 16; ++q) {
            const int e  = q * 256 + tid;     // float4 idx in [0,4096)
            const int jj = e >> 5;
            const int c4 = e & 31;
            const float4 v = *(const float4*)&m2z[(b * K + jt * 128 + jj) * Z + c4 * 4];
            h2 p0; p0.x = (_Float16)v.x; p0.y = (_Float16)v.y;
            h2 p1; p1.x = (_Float16)v.z; p1.y = (_Float16)v.w;
            sv[jj][c4 * 2]     = p0;
            sv[jj][c4 * 2 + 1] = p1;
        }
        __syncthreads();

        const unsigned int* mr0 = &smask[2 * wv][jt * 128];
        const unsigned int* mr1 = &smask[2 * wv + 1][jt * 128];
        for (int jj = 0; jj < 128; ++jj) {
            const h2 v = sv[jj][lane];
            U32H2 f0, f1; f0.u = mr0[jj]; f1.u = mr1[jj];
            acc0 = __builtin_elementwise_max(acc0, v + f0.h);
            acc1 = __builtin_elementwise_max(acc1, v + f1.h);
        }
    }

    {   // m rows -> xs[:, 128..255] = relu(m1z + max)
        const int r0 = 2 * wv, r1 = 2 * wv + 1;
        const float2 ma = *(const float2*)&m1z[(b * K + i0 + r0) * Z + 2 * lane];
        const float2 mb = *(const float2*)&m1z[(b * K + i0 + r1) * Z + 2 * lane];
        xs[r0][Z + 2 * lane]     = fmaxf(ma.x + (float)acc0.x, 0.0f);
        xs[r0][Z + 2 * lane + 1] = fmaxf(ma.y + (float)acc0.y, 0.0f);
        xs[r1][Z + 2 * lane]     = fmaxf(mb.x + (float)acc1.x, 0.0f);
        xs[r1][Z + 2 * lane + 1] = fmaxf(mb.y + (float)acc1.y, 0.0f);
    }

    // ---- concat GEMM: out[row, o] = relu(sum_k xs[row][k] * Wu[o][k] + bu[o])
    const int o  = tid & 127;
    const int rh = tid >> 7;
    float acc[4];
    const float bb = bu[o];
#pragma unroll
    for (int r = 0; r < 4; ++r) acc[r] = bb;

    for (int kc = 0; kc < 8; ++kc) {
        __syncthreads();              // sv/xs writes done (kc=0), prev chunk consumed
#pragma unroll
        for (int q = 0; q < 8; ++q) { // stage Wu chunk [128][32], coalesced float2
            const int f  = q * 256 + tid;
            const int oo = f >> 4;
            const int jj = (f & 15) * 2;
            *(float2*)&swu[oo][jj] = *(const float2*)&Wu[oo * (2 * Z) + kc * 32 + jj];
        }
        __syncthreads();
#pragma unroll
        for (int j2 = 0; j2 < 16; ++j2) {
            const float2 w = *(const float2*)&swu[o][j2 * 2];
#pragma unroll
            for (int r = 0; r < 4; ++r) {
                const float2 xv = *(const float2*)&xs[rh * 4 + r][kc * 32 + j2 * 2];
                acc[r] += xv.x * w.x + xv.y * w.y;
            }
        }
    }
#pragma unroll
    for (int r = 0; r < 4; ++r)
        out[(b * K + i0 + rh * 4 + r) * H + o] = fmaxf(acc[r], 0.0f);
}

extern "C" void kernel_launch(void* const* d_in, const int* in_sizes, int n_in,
                              void* d_out, int out_size, void* d_ws, size_t ws_size,
                              hipStream_t stream) {
    const float* z  = (const float*)d_in[0];
    const int*   P  = (const int*)d_in[1];
    const float* W1 = (const float*)d_in[2];
    const float* b1 = (const float*)d_in[3];
    const float* W2 = (const float*)d_in[4];
    const float* b2 = (const float*)d_in[5];
    const float* Wu = (const float*)d_in[6];
    const float* bu = (const float*)d_in[7];

    float* m1z = (float*)d_ws;             // [B*K*Z] f32
    float* m2z = m1z + B * K * Z;          // [B*K*Z] f32

    // MEASUREMENT PROBE (this round): launch the identical idempotent sequence
    // twice. dur_us(R6) - dur_us(R5) == t(k_lin) + t(k_maxout), giving per-kernel
    // cost hidden below the harness's 41 us fill dispatches in rocprof top-5.
    k_lin<<<(B * K) / 8, 256, 0, stream>>>(z, W1, b1, W2, b2, m1z, m2z);
    k_maxout<<<dim3(B, K / 8), 256, 0, stream>>>(z, P, m1z, m2z, Wu, bu, (float*)d_out);
    k_lin<<<(B * K) / 8, 256, 0, stream>>>(z, W1, b1, W2, b2, m1z, m2z);
    k_maxout<<<dim3(B, K / 8), 256, 0, stream>>>(z, P, m1z, m2z, Wu, bu, (float*)d_out);
}

// Round 7
// 91.136 us; speedup vs baseline: 1.7013x; 1.7013x over previous
//
#include <hip/hip_runtime.h>

#define B 16
#define K 256
#define Z 128
#define H 128

typedef _Float16 h2 __attribute__((ext_vector_type(2)));
typedef _Float16 h4 __attribute__((ext_vector_type(4)));
typedef _Float16 half8 __attribute__((ext_vector_type(8)));
typedef float f32x4 __attribute__((ext_vector_type(4)));
union UH2 { unsigned int u; h2 h; };

// ---------------- K0: convert W1, W2, Wu f32 -> f16 (flat) ----------------
__global__ __launch_bounds__(256) void k_cvt(
    const float* __restrict__ W1, const float* __restrict__ W2,
    const float* __restrict__ Wu,
    _Float16* __restrict__ w1f, _Float16* __restrict__ w2f,
    _Float16* __restrict__ wuf)
{
    const int i4 = (blockIdx.x * 256 + threadIdx.x) * 4;   // [0, 65536)
    const float* src; _Float16* dst; int off;
    if (i4 < 16384)      { src = W1; dst = w1f; off = i4; }
    else if (i4 < 32768) { src = W2; dst = w2f; off = i4 - 16384; }
    else                 { src = Wu; dst = wuf; off = i4 - 32768; }
    const float4 v = *(const float4*)(src + off);
    h4 o; o.x = (_Float16)v.x; o.y = (_Float16)v.y;
    o.z = (_Float16)v.z; o.w = (_Float16)v.w;
    *(h4*)(dst + off) = o;
}

// ---------------- K1: m1z/m2z = z@W^T + b  via MFMA f16, f16 outputs -------
// grid 256 blocks x 16 rows; block 256 = 4 waves = (mat: W1/W2) x (n-half)
__global__ __launch_bounds__(256) void k_lin(
    const float* __restrict__ z,
    const _Float16* __restrict__ w1f, const _Float16* __restrict__ w2f,
    const float* __restrict__ b1, const float* __restrict__ b2,
    _Float16* __restrict__ m1f, _Float16* __restrict__ m2f)
{
    const int row0 = blockIdx.x * 16;
    const int tid = threadIdx.x;
    const int lane = tid & 63, wave = tid >> 6;
    const int mat = wave >> 1, nh = wave & 1;
    const int mcol = lane & 15, quad = lane >> 4;

    const _Float16* wf  = mat ? w2f : w1f;
    const float*   bias = mat ? b2 : b1;
    _Float16*      dst  = mat ? m2f : m1f;

    // A-frags: A[m=mcol][k = ks*32 + quad*8 + j], from f32 z, cvt to f16
    half8 a[4];
#pragma unroll
    for (int ks = 0; ks < 4; ++ks) {
        const float* p = z + (row0 + mcol) * Z + ks * 32 + quad * 8;
        const float4 v0 = *(const float4*)p;
        const float4 v1 = *(const float4*)(p + 4);
        half8 t;
        t[0]=(_Float16)v0.x; t[1]=(_Float16)v0.y; t[2]=(_Float16)v0.z; t[3]=(_Float16)v0.w;
        t[4]=(_Float16)v1.x; t[5]=(_Float16)v1.y; t[6]=(_Float16)v1.z; t[7]=(_Float16)v1.w;
        a[ks] = t;
    }

    f32x4 acc[4];
#pragma unroll
    for (int nt = 0; nt < 4; ++nt) {
        const float bv = bias[nh * 64 + nt * 16 + mcol];
        acc[nt][0] = bv; acc[nt][1] = bv; acc[nt][2] = bv; acc[nt][3] = bv;
    }

#pragma unroll
    for (int ks = 0; ks < 4; ++ks) {
#pragma unroll
        for (int nt = 0; nt < 4; ++nt) {
            const int n = nh * 64 + nt * 16 + mcol;
            // B[k][n] = W[n][k]: 8 consecutive k from W row n
            const half8 bb = *(const half8*)(wf + n * Z + ks * 32 + quad * 8);
            acc[nt] = __builtin_amdgcn_mfma_f32_16x16x32_f16(a[ks], bb, acc[nt], 0, 0, 0);
        }
    }
    // C/D: col = lane&15, row = quad*4 + reg  [m89-verified mapping]
#pragma unroll
    for (int nt = 0; nt < 4; ++nt) {
        const int n = nh * 64 + nt * 16 + mcol;
#pragma unroll
        for (int r = 0; r < 4; ++r)
            dst[(row0 + quad * 4 + r) * Z + n] = (_Float16)acc[nt][r];
    }
}

// ---------------- K2 (fused): tropical max + concat MFMA GEMM --------------
// grid (b:16, itile:16); block 256 = 4 waves = (row-half: 8 i) x (j-half: 128 j)
__global__ __launch_bounds__(256) void k_fused(
    const float* __restrict__ z, const int* __restrict__ P,
    const _Float16* __restrict__ m1f, const _Float16* __restrict__ m2f,
    const _Float16* __restrict__ wuf, const float* __restrict__ bu,
    float* __restrict__ out)
{
    const int b = blockIdx.x, i0 = blockIdx.y * 16;
    const int tid = threadIdx.x, lane = tid & 63, wave = tid >> 6;

    __shared__ unsigned int smask[256][8];            // 8 KB: 16 f16 per j
    __shared__ __align__(16) _Float16 xs[16][264];    // 8.25 KB (pad 8 f16)
    __shared__ unsigned int part[2][16][64];          // 8 KB partial maxima

    {   // xs z-half: thread (r = tid>>4, c = tid&15): 8 f32 -> 8 f16
        const int r = tid >> 4, c = tid & 15;
        const float* p = z + (b * K + i0 + r) * Z + c * 8;
        const float4 v0 = *(const float4*)p;
        const float4 v1 = *(const float4*)(p + 4);
        half8 t;
        t[0]=(_Float16)v0.x; t[1]=(_Float16)v0.y; t[2]=(_Float16)v0.z; t[3]=(_Float16)v0.w;
        t[4]=(_Float16)v1.x; t[5]=(_Float16)v1.y; t[6]=(_Float16)v1.z; t[7]=(_Float16)v1.w;
        *(half8*)&xs[r][c * 8] = t;
    }
#pragma unroll
    for (int g = 0; g < 4; ++g) {     // smask: 0 or f16(-inf) per (j, row)
        const int idx = g * 256 + tid;
        const int j = idx >> 2, q = idx & 3;
        const int4 pv = *(const int4*)(P + (b * K + j) * K + i0 + q * 4);
        const unsigned w0 = (pv.x ? 0u : 0xFC00u) | ((pv.y ? 0u : 0xFC00u) << 16);
        const unsigned w1 = (pv.z ? 0u : 0xFC00u) | ((pv.w ? 0u : 0xFC00u) << 16);
        smask[j][q * 2]     = w0;
        smask[j][q * 2 + 1] = w1;
    }
    __syncthreads();

    // ---- tropical: wave (rh, jh): rows rh*8..+8, j in [jh*128, +128)
    const int rh = wave & 1, jh = wave >> 1;
    const unsigned int* m2u = (const unsigned int*)m2f + (b * K + jh * 128) * 64 + lane;
    UH2 ninf; ninf.u = 0xFC00FC00u;
    h2 acc[8];
#pragma unroll
    for (int r = 0; r < 8; ++r) acc[r] = ninf.h;

#pragma unroll 4
    for (int jj = 0; jj < 128; ++jj) {
        UH2 v; v.u = m2u[jj * 64];                        // d-pair, L2-resident
        const uint4 mw = *(const uint4*)&smask[jh * 128 + jj][rh * 4];
        UH2 lo, hi;
        lo.u = __builtin_amdgcn_perm(mw.x, mw.x, 0x01000100u);
        hi.u = __builtin_amdgcn_perm(mw.x, mw.x, 0x03020302u);
        acc[0] = __builtin_elementwise_max(acc[0], v.h + lo.h);
        acc[1] = __builtin_elementwise_max(acc[1], v.h + hi.h);
        lo.u = __builtin_amdgcn_perm(mw.y, mw.y, 0x01000100u);
        hi.u = __builtin_amdgcn_perm(mw.y, mw.y, 0x03020302u);
        acc[2] = __builtin_elementwise_max(acc[2], v.h + lo.h);
        acc[3] = __builtin_elementwise_max(acc[3], v.h + hi.h);
        lo.u = __builtin_amdgcn_perm(mw.z, mw.z, 0x01000100u);
        hi.u = __builtin_amdgcn_perm(mw.z, mw.z, 0x03020302u);
        acc[4] = __builtin_elementwise_max(acc[4], v.h + lo.h);
        acc[5] = __builtin_elementwise_max(acc[5], v.h + hi.h);
        lo.u = __builtin_amdgcn_perm(mw.w, mw.w, 0x01000100u);
        hi.u = __builtin_amdgcn_perm(mw.w, mw.w, 0x03020302u);
        acc[6] = __builtin_elementwise_max(acc[6], v.h + lo.h);
        acc[7] = __builtin_elementwise_max(acc[7], v.h + hi.h);
    }
#pragma unroll
    for (int r = 0; r < 8; ++r) { UH2 t; t.h = acc[r]; part[jh][rh * 8 + r][lane] = t.u; }
    __syncthreads();

    {   // combine 2 j-halves + m1z + relu -> xs m-half
        const int r = tid >> 4, p0 = (tid & 15) * 4;
        const uint4 pa = *(const uint4*)&part[0][r][p0];
        const uint4 pc = *(const uint4*)&part[1][r][p0];
        const uint4 m1 = *(const uint4*)((const unsigned int*)m1f + (b * K + i0 + r) * 64 + p0);
        const h2 z2 = { (_Float16)0.0f, (_Float16)0.0f };
        uint4 o;
        {
            UH2 x, y, m, t;
            x.u=pa.x; y.u=pc.x; m.u=m1.x;
            t.h = __builtin_elementwise_max(m.h + __builtin_elementwise_max(x.h, y.h), z2); o.x=t.u;
            x.u=pa.y; y.u=pc.y; m.u=m1.y;
            t.h = __builtin_elementwise_max(m.h + __builtin_elementwise_max(x.h, y.h), z2); o.y=t.u;
            x.u=pa.z; y.u=pc.z; m.u=m1.z;
            t.h = __builtin_elementwise_max(m.h + __builtin_elementwise_max(x.h, y.h), z2); o.z=t.u;
            x.u=pa.w; y.u=pc.w; m.u=m1.w;
            t.h = __builtin_elementwise_max(m.h + __builtin_elementwise_max(x.h, y.h), z2); o.w=t.u;
        }
        *(uint4*)&xs[r][128 + 2 * p0] = o;
    }
    __syncthreads();

    // ---- concat MFMA: out[i, n] = relu(xs[i,:] . Wu[n,:] + bu[n])
    const int mcol = lane & 15, quad = lane >> 4;
    half8 a[8];
#pragma unroll
    for (int ks = 0; ks < 8; ++ks)
        a[ks] = *(const half8*)&xs[mcol][ks * 32 + quad * 8];
#pragma unroll
    for (int s = 0; s < 2; ++s) {
        const int n = wave * 32 + s * 16 + mcol;
        const float bv = bu[n];
        f32x4 c2; c2[0]=bv; c2[1]=bv; c2[2]=bv; c2[3]=bv;
#pragma unroll
        for (int ks = 0; ks < 8; ++ks) {
            const half8 bb = *(const half8*)(wuf + n * 256 + ks * 32 + quad * 8);
            c2 = __builtin_amdgcn_mfma_f32_16x16x32_f16(a[ks], bb, c2, 0, 0, 0);
        }
#pragma unroll
        for (int r = 0; r < 4; ++r)
            out[(b * K + i0 + quad * 4 + r) * H + n] = fmaxf(c2[r], 0.0f);
    }
}

extern "C" void kernel_launch(void* const* d_in, const int* in_sizes, int n_in,
                              void* d_out, int out_size, void* d_ws, size_t ws_size,
                              hipStream_t stream) {
    const float* z  = (const float*)d_in[0];
    const int*   P  = (const int*)d_in[1];
    const float* W1 = (const float*)d_in[2];
    const float* b1 = (const float*)d_in[3];
    const float* W2 = (const float*)d_in[4];
    const float* b2 = (const float*)d_in[5];
    const float* Wu = (const float*)d_in[6];
    const float* bu = (const float*)d_in[7];

    char* w = (char*)d_ws;
    _Float16* w1f = (_Float16*)(w);                       // 32 KB
    _Float16* w2f = (_Float16*)(w + 32768);               // 32 KB
    _Float16* wuf = (_Float16*)(w + 65536);               // 64 KB
    _Float16* m1f = (_Float16*)(w + 131072);              // 1 MB
    _Float16* m2f = (_Float16*)(w + 131072 + 1048576);    // 1 MB

    k_cvt<<<64, 256, 0, stream>>>(W1, W2, Wu, w1f, w2f, wuf);
    k_lin<<<256, 256, 0, stream>>>(z, w1f, w2f, b1, b2, m1f, m2f);
    k_fused<<<dim3(16, 16), 256, 0, stream>>>(z, P, m1f, m2f, wuf, bu, (float*)d_out);
}

// Round 8
// 88.265 us; speedup vs baseline: 1.7566x; 1.0325x over previous
//
#include <hip/hip_runtime.h>

#define B 16
#define K 256
#define Z 128
#define H 128

typedef _Float16 h2 __attribute__((ext_vector_type(2)));
typedef _Float16 half8 __attribute__((ext_vector_type(8)));
typedef float f32x4 __attribute__((ext_vector_type(4)));
union UH2 { unsigned int u; h2 h; };

// convert 8 consecutive f32 -> half8 (v_cvt_pkrtz x4)
__device__ __forceinline__ half8 cvt8(const float* __restrict__ p) {
    const float4 v0 = *(const float4*)p;
    const float4 v1 = *(const float4*)(p + 4);
    half8 t;
    t[0] = (_Float16)v0.x; t[1] = (_Float16)v0.y;
    t[2] = (_Float16)v0.z; t[3] = (_Float16)v0.w;
    t[4] = (_Float16)v1.x; t[5] = (_Float16)v1.y;
    t[6] = (_Float16)v1.z; t[7] = (_Float16)v1.w;
    return t;
}

// ---------------- K1: m1z/m2z = z@W^T + b via MFMA f16 (f16 out) ----------
// grid 256 x 16 rows; block 512 = 8 waves = (mat: W1/W2) x (n-group of 32)
__global__ __launch_bounds__(512) void k_lin(
    const float* __restrict__ z,
    const float* __restrict__ W1, const float* __restrict__ b1,
    const float* __restrict__ W2, const float* __restrict__ b2,
    _Float16* __restrict__ m1f, _Float16* __restrict__ m2f)
{
    const int row0 = blockIdx.x * 16;
    const int tid = threadIdx.x;
    const int lane = tid & 63, wave = tid >> 6;
    const int mat = wave >> 2;          // 0: W1 path, 1: W2 path
    const int ng  = wave & 3;           // n-group: 32 outputs
    const int mcol = lane & 15, quad = lane >> 4;

    const float* W  = mat ? W2 : W1;
    const float* bs = mat ? b2 : b1;
    _Float16*   dst = mat ? m2f : m1f;

    // A-frags: A[m=mcol][k=ks*32+quad*8+j] from f32 z
    half8 a[4];
#pragma unroll
    for (int ks = 0; ks < 4; ++ks)
        a[ks] = cvt8(z + (row0 + mcol) * Z + ks * 32 + quad * 8);

    f32x4 acc[2];
#pragma unroll
    for (int nt = 0; nt < 2; ++nt) {
        const float bv = bs[ng * 32 + nt * 16 + mcol];
        acc[nt][0] = bv; acc[nt][1] = bv; acc[nt][2] = bv; acc[nt][3] = bv;
    }

#pragma unroll
    for (int ks = 0; ks < 4; ++ks) {
#pragma unroll
        for (int nt = 0; nt < 2; ++nt) {
            const int n = ng * 32 + nt * 16 + mcol;
            const half8 bb = cvt8(W + n * Z + ks * 32 + quad * 8);  // B[k][n]=W[n][k]
            acc[nt] = __builtin_amdgcn_mfma_f32_16x16x32_f16(a[ks], bb, acc[nt], 0, 0, 0);
        }
    }
    // C/D: col = lane&15, row = quad*4 + reg
#pragma unroll
    for (int nt = 0; nt < 2; ++nt) {
        const int n = ng * 32 + nt * 16 + mcol;
#pragma unroll
        for (int r = 0; r < 4; ++r)
            dst[(row0 + quad * 4 + r) * Z + n] = (_Float16)acc[nt][r];
    }
}

// ---------------- K2 (fused): tropical max + concat MFMA GEMM --------------
// grid (b:16, itile:16); block 512 = 8 waves = (row-half: 8 i) x (j-quarter: 64 j)
__global__ __launch_bounds__(512) void k_fused(
    const float* __restrict__ z, const int* __restrict__ P,
    const _Float16* __restrict__ m1f, const _Float16* __restrict__ m2f,
    const float* __restrict__ Wu, const float* __restrict__ bu,
    float* __restrict__ out)
{
    const int b = blockIdx.x, i0 = blockIdx.y * 16;
    const int tid = threadIdx.x, lane = tid & 63, wave = tid >> 6;

    __shared__ unsigned int smask[256][16];          // 16 KB: h2 mask (0 / -inf,-inf) per (j,row)
    __shared__ __align__(16) _Float16 xs[16][264];   // 8.25 KB concat rows (+pad)
    __shared__ unsigned int part[4][16][64];         // 16 KB partial maxima (h2 as u32)

    {   // xs z-half: 16 rows x 128 f16; thread (r=tid>>5, c=(tid&31)*4)
        const int r = tid >> 5, c = (tid & 31) * 4;
        const float4 v = *(const float4*)&z[(b * K + i0 + r) * Z + c];
        UH2 p0, p1;
        p0.h[0] = (_Float16)v.x; p0.h[1] = (_Float16)v.y;
        p1.h[0] = (_Float16)v.z; p1.h[1] = (_Float16)v.w;
        uint2 o; o.x = p0.u; o.y = p1.u;
        *(uint2*)&xs[r][c] = o;
    }
#pragma unroll
    for (int g = 0; g < 2; ++g) {   // smask: 1024 (j,q) items over 512 threads
        const int idx = g * 512 + tid;
        const int j = idx >> 2, q = idx & 3;
        const int4 pv = *(const int4*)(P + (b * K + j) * K + i0 + q * 4);
        uint4 o;
        o.x = pv.x ? 0u : 0xFC00FC00u;
        o.y = pv.y ? 0u : 0xFC00FC00u;
        o.z = pv.z ? 0u : 0xFC00FC00u;
        o.w = pv.w ? 0u : 0xFC00FC00u;
        *(uint4*)&smask[j][q * 4] = o;
    }
    __syncthreads();

    // ---- tropical: wave (rh, jq): rows rh*8..+8, j in [jq*64, +64)
    const int rh = wave & 1, jq = wave >> 1;
    const unsigned int* m2u = (const unsigned int*)m2f + (b * K + jq * 64) * 64 + lane;
    UH2 ninf; ninf.u = 0xFC00FC00u;
    h2 acc[8];
#pragma unroll
    for (int r = 0; r < 8; ++r) acc[r] = ninf.h;

#pragma unroll 4
    for (int jj = 0; jj < 64; ++jj) {
        UH2 v; v.u = m2u[jj * 64];                       // d-pair (L2-resident)
        const uint4 ma = *(const uint4*)&smask[jq * 64 + jj][rh * 8];
        const uint4 mb = *(const uint4*)&smask[jq * 64 + jj][rh * 8 + 4];
        UH2 t;
        t.u = ma.x; acc[0] = __builtin_elementwise_max(acc[0], v.h + t.h);
        t.u = ma.y; acc[1] = __builtin_elementwise_max(acc[1], v.h + t.h);
        t.u = ma.z; acc[2] = __builtin_elementwise_max(acc[2], v.h + t.h);
        t.u = ma.w; acc[3] = __builtin_elementwise_max(acc[3], v.h + t.h);
        t.u = mb.x; acc[4] = __builtin_elementwise_max(acc[4], v.h + t.h);
        t.u = mb.y; acc[5] = __builtin_elementwise_max(acc[5], v.h + t.h);
        t.u = mb.z; acc[6] = __builtin_elementwise_max(acc[6], v.h + t.h);
        t.u = mb.w; acc[7] = __builtin_elementwise_max(acc[7], v.h + t.h);
    }
#pragma unroll
    for (int r = 0; r < 8; ++r) { UH2 t; t.h = acc[r]; part[jq][rh * 8 + r][lane] = t.u; }
    __syncthreads();

    {   // combine 4 j-quarters + m1z + relu -> xs m-half
        const int r = tid >> 5, c = (tid & 31) * 2;      // c: d-pair index (0..62)
        const uint2 q0 = *(const uint2*)&part[0][r][c];
        const uint2 q1 = *(const uint2*)&part[1][r][c];
        const uint2 q2 = *(const uint2*)&part[2][r][c];
        const uint2 q3 = *(const uint2*)&part[3][r][c];
        const uint2 m1 = *(const uint2*)((const unsigned int*)m1f + (b * K + i0 + r) * 64 + c);
        const h2 z2 = { (_Float16)0.0f, (_Float16)0.0f };
        UH2 a0, a1, a2, a3, m, t;
        uint2 o;
        a0.u = q0.x; a1.u = q1.x; a2.u = q2.x; a3.u = q3.x; m.u = m1.x;
        t.h = __builtin_elementwise_max(
            m.h + __builtin_elementwise_max(__builtin_elementwise_max(a0.h, a1.h),
                                            __builtin_elementwise_max(a2.h, a3.h)), z2);
        o.x = t.u;
        a0.u = q0.y; a1.u = q1.y; a2.u = q2.y; a3.u = q3.y; m.u = m1.y;
        t.h = __builtin_elementwise_max(
            m.h + __builtin_elementwise_max(__builtin_elementwise_max(a0.h, a1.h),
                                            __builtin_elementwise_max(a2.h, a3.h)), z2);
        o.y = t.u;
        *(uint2*)&xs[r][128 + 2 * c] = o;
    }
    __syncthreads();

    // ---- concat MFMA: out[i, n] = relu(xs[i,:] . Wu[n,:] + bu[n]); wave -> 16 n
    const int mcol = lane & 15, quad = lane >> 4;
    const int n = wave * 16 + mcol;
    half8 a[8];
#pragma unroll
    for (int ks = 0; ks < 8; ++ks)
        a[ks] = *(const half8*)&xs[mcol][ks * 32 + quad * 8];
    const float bv = bu[n];
    f32x4 c2; c2[0] = bv; c2[1] = bv; c2[2] = bv; c2[3] = bv;
#pragma unroll
    for (int ks = 0; ks < 8; ++ks) {
        const half8 bb = cvt8(Wu + n * 256 + ks * 32 + quad * 8);
        c2 = __builtin_amdgcn_mfma_f32_16x16x32_f16(a[ks], bb, c2, 0, 0, 0);
    }
#pragma unroll
    for (int r = 0; r < 4; ++r)
        out[(b * K + i0 + quad * 4 + r) * H + n] = fmaxf(c2[r], 0.0f);
}

extern "C" void kernel_launch(void* const* d_in, const int* in_sizes, int n_in,
                              void* d_out, int out_size, void* d_ws, size_t ws_size,
                              hipStream_t stream) {
    const float* z  = (const float*)d_in[0];
    const int*   P  = (const int*)d_in[1];
    const float* W1 = (const float*)d_in[2];
    const float* b1 = (const float*)d_in[3];
    const float* W2 = (const float*)d_in[4];
    const float* b2 = (const float*)d_in[5];
    const float* Wu = (const float*)d_in[6];
    const float* bu = (const float*)d_in[7];

    _Float16* m1f = (_Float16*)d_ws;               // 1 MB
    _Float16* m2f = m1f + B * K * Z;               // 1 MB

    k_lin<<<256, 512, 0, stream>>>(z, W1, b1, W2, b2, m1f, m2f);
    k_fused<<<dim3(16, 16), 512, 0, stream>>>(z, P, m1f, m2f, Wu, bu, (float*)d_out);
}